// Round 1
// baseline (1974.005 us; speedup 1.0000x reference)
//
#include <hip/hip_runtime.h>
#include <cmath>

typedef float f4 __attribute__((ext_vector_type(4)));

#define TOK   2048
#define NBAT  4
#define NH    16
#define DH    64
#define MODEL 1024
#define MTOT  (NBAT*TOK)          // 8192
#define NQKV  (3*MODEL)           // 3072
#define ATT_SCALE 0.125f
#define BUF_ELEMS ((size_t)MTOT*MODEL)   // 8388608 floats per q/k/v/attn buffer

// ---------------------------------------------------------------------------
// GEMM1: x[8192][1024] @ w_qkv[1024][3072] -> q/k/v buffers in [b*h][n][64]
// 128x128 tile, BK=8, 256 threads, 8x8 per-thread microtile (split 4+4).
// ---------------------------------------------------------------------------
__global__ __launch_bounds__(256)
void qkv_gemm_k(const float* __restrict__ A, const float* __restrict__ B,
                float* __restrict__ qb, float* __restrict__ kb, float* __restrict__ vb)
{
    __shared__ float As[8][128];   // As[k][m] (transposed)
    __shared__ float Bs[8][128];   // Bs[k][n]
    const int tid = threadIdx.x;
    const int bm = blockIdx.x << 7;
    const int bn = blockIdx.y << 7;
    const int tx4 = (tid & 15) << 2;
    const int ty4 = (tid >> 4) << 2;

    const int arow = bm + (tid >> 1);      // 2 threads per row, float4 each
    const int akq  = (tid & 1) << 2;
    const int bkk  = tid >> 5;             // 0..7
    const int bcq  = (tid & 31) << 2;

    f4 aReg = *(const f4*)&A[(size_t)arow * MODEL + akq];
    f4 bReg = *(const f4*)&B[(size_t)bkk * NQKV + bn + bcq];

    float acc[8][8];
    #pragma unroll
    for (int i = 0; i < 8; ++i)
        #pragma unroll
        for (int j = 0; j < 8; ++j) acc[i][j] = 0.f;

    const int nsteps = MODEL / 8;
    for (int s = 0; s < nsteps; ++s) {
        __syncthreads();
        As[akq + 0][tid >> 1] = aReg[0];
        As[akq + 1][tid >> 1] = aReg[1];
        As[akq + 2][tid >> 1] = aReg[2];
        As[akq + 3][tid >> 1] = aReg[3];
        *(f4*)&Bs[bkk][bcq] = bReg;
        __syncthreads();
        if (s + 1 < nsteps) {
            const int k0 = (s + 1) << 3;
            aReg = *(const f4*)&A[(size_t)arow * MODEL + k0 + akq];
            bReg = *(const f4*)&B[(size_t)(k0 + bkk) * NQKV + bn + bcq];
        }
        #pragma unroll
        for (int kk = 0; kk < 8; ++kk) {
            f4 a0 = *(const f4*)&As[kk][ty4];
            f4 a1 = *(const f4*)&As[kk][64 + ty4];
            f4 b0 = *(const f4*)&Bs[kk][tx4];
            f4 b1 = *(const f4*)&Bs[kk][64 + tx4];
            #pragma unroll
            for (int i = 0; i < 4; ++i)
                #pragma unroll
                for (int j = 0; j < 4; ++j) {
                    acc[i][j]         += a0[i] * b0[j];
                    acc[i][j + 4]     += a0[i] * b1[j];
                    acc[i + 4][j]     += a1[i] * b0[j];
                    acc[i + 4][j + 4] += a1[i] * b1[j];
                }
        }
    }

    // scatter epilogue: column c -> (q/k/v, head, d); row -> (batch, token)
    #pragma unroll
    for (int ii = 0; ii < 8; ++ii) {
        const int r  = bm + ((ii < 4) ? (ty4 + ii) : (64 + ty4 + ii - 4));
        const int bb = r >> 11;            // /2048
        const int nn = r & (TOK - 1);
        #pragma unroll
        for (int jj = 0; jj < 8; ++jj) {
            const int c   = bn + ((jj < 4) ? (tx4 + jj) : (64 + tx4 + jj - 4));
            const int sel = c >> 10;
            const int cc  = c & 1023;
            const int h   = cc >> 6;
            const int dd  = cc & 63;
            const size_t dst = (((size_t)(bb * NH + h) * TOK) + nn) * DH + dd;
            float* p = (sel == 0) ? qb : (sel == 1) ? kb : vb;
            p[dst] = acc[ii][jj];
        }
    }
}

// ---------------------------------------------------------------------------
// Flash-style fp32 attention. Block = (head, 64-query tile), 256 threads.
// Q/K row-major [64][68] in LDS, V transposed [d][n]. P staged through the
// K buffer (aliased; barriers separate the uses).
// ---------------------------------------------------------------------------
__global__ __launch_bounds__(256)
void attn_k(const float* __restrict__ qb, const float* __restrict__ kb,
            const float* __restrict__ vb, float* __restrict__ ob)
{
    __shared__ float Qs[64][68];
    __shared__ float KPs[64][68];
    __shared__ float Vst[64][68];

    const int tid = threadIdx.x;
    const int tx = tid & 15;
    const int ty = tid >> 4;
    const int bh = blockIdx.x;           // 0..63 = b*16+h
    const int q0 = blockIdx.y << 6;

    const size_t base = (size_t)bh * TOK * DH;
    const float* Q = qb + base;
    const float* K = kb + base;
    const float* V = vb + base;

    #pragma unroll
    for (int r = 0; r < 4; ++r) {
        const int i4  = tid + (r << 8);
        const int row = i4 >> 4;
        const int d4  = (i4 & 15) << 2;
        *(f4*)&Qs[row][d4] = *(const f4*)&Q[(size_t)(q0 + row) * DH + d4];
    }

    float m_i[4], l_i[4], o[4][4];
    #pragma unroll
    for (int i = 0; i < 4; ++i) {
        m_i[i] = -1e30f;
        l_i[i] = 0.f;
        #pragma unroll
        for (int j = 0; j < 4; ++j) o[i][j] = 0.f;
    }

    for (int kblk = 0; kblk < TOK / 64; ++kblk) {
        const int k0 = kblk << 6;
        __syncthreads();   // prior PV reads of KPs/Vst done
        #pragma unroll
        for (int r = 0; r < 4; ++r) {
            const int i4  = tid + (r << 8);
            const int row = i4 >> 4;
            const int d4  = (i4 & 15) << 2;
            *(f4*)&KPs[row][d4] = *(const f4*)&K[(size_t)(k0 + row) * DH + d4];
            f4 vv = *(const f4*)&V[(size_t)(k0 + row) * DH + d4];
            Vst[d4 + 0][row] = vv[0];
            Vst[d4 + 1][row] = vv[1];
            Vst[d4 + 2][row] = vv[2];
            Vst[d4 + 3][row] = vv[3];
        }
        __syncthreads();

        // S = Q K^T * scale ; rows = ty*4+i, cols = tx+16j
        float s[4][4];
        #pragma unroll
        for (int i = 0; i < 4; ++i)
            #pragma unroll
            for (int j = 0; j < 4; ++j) s[i][j] = 0.f;

        #pragma unroll
        for (int kq = 0; kq < 16; ++kq) {
            f4 a[4], bk[4];
            #pragma unroll
            for (int i = 0; i < 4; ++i) a[i] = *(const f4*)&Qs[(ty << 2) + i][kq << 2];
            #pragma unroll
            for (int j = 0; j < 4; ++j) bk[j] = *(const f4*)&KPs[tx + (j << 4)][kq << 2];
            #pragma unroll
            for (int i = 0; i < 4; ++i)
                #pragma unroll
                for (int j = 0; j < 4; ++j)
                    #pragma unroll
                    for (int l = 0; l < 4; ++l)
                        s[i][j] += a[i][l] * bk[j][l];
        }

        // online softmax update (row reductions across the 16 tx lanes)
        float p[4][4];
        #pragma unroll
        for (int i = 0; i < 4; ++i) {
            #pragma unroll
            for (int j = 0; j < 4; ++j) s[i][j] *= ATT_SCALE;
            float rm = fmaxf(fmaxf(s[i][0], s[i][1]), fmaxf(s[i][2], s[i][3]));
            rm = fmaxf(rm, __shfl_xor(rm, 1));
            rm = fmaxf(rm, __shfl_xor(rm, 2));
            rm = fmaxf(rm, __shfl_xor(rm, 4));
            rm = fmaxf(rm, __shfl_xor(rm, 8));
            const float mnew = fmaxf(m_i[i], rm);
            const float sf = __expf(m_i[i] - mnew);
            float rs = 0.f;
            #pragma unroll
            for (int j = 0; j < 4; ++j) { p[i][j] = __expf(s[i][j] - mnew); rs += p[i][j]; }
            rs += __shfl_xor(rs, 1);
            rs += __shfl_xor(rs, 2);
            rs += __shfl_xor(rs, 4);
            rs += __shfl_xor(rs, 8);
            l_i[i] = l_i[i] * sf + rs;
            m_i[i] = mnew;
            #pragma unroll
            for (int j = 0; j < 4; ++j) o[i][j] *= sf;
        }

        __syncthreads();   // all S reads of KPs complete
        #pragma unroll
        for (int i = 0; i < 4; ++i)
            #pragma unroll
            for (int j = 0; j < 4; ++j)
                KPs[(ty << 2) + i][tx + (j << 4)] = p[i][j];
        __syncthreads();

        // O += P V ; O cols = d = tx+16j (Vst is [d][n])
        #pragma unroll
        for (int kq = 0; kq < 16; ++kq) {
            f4 pa[4], vv[4];
            #pragma unroll
            for (int i = 0; i < 4; ++i) pa[i] = *(const f4*)&KPs[(ty << 2) + i][kq << 2];
            #pragma unroll
            for (int j = 0; j < 4; ++j) vv[j] = *(const f4*)&Vst[tx + (j << 4)][kq << 2];
            #pragma unroll
            for (int i = 0; i < 4; ++i)
                #pragma unroll
                for (int j = 0; j < 4; ++j)
                    #pragma unroll
                    for (int l = 0; l < 4; ++l)
                        o[i][j] += pa[i][l] * vv[j][l];
        }
    }

    // write [b][n][h*64+d]
    const int b = bh >> 4;
    const int h = bh & 15;
    #pragma unroll
    for (int i = 0; i < 4; ++i) {
        const float inv = 1.f / l_i[i];
        const size_t gr = (size_t)(b * TOK + q0 + (ty << 2) + i);
        #pragma unroll
        for (int j = 0; j < 4; ++j) {
            const int col = (h << 6) + tx + (j << 4);
            ob[gr * MODEL + col] = o[i][j] * inv;
        }
    }
}

// ---------------------------------------------------------------------------
// GEMM2: attn_out[8192][1024] @ w_out[1024][1024] + b_out -> d_out
// ---------------------------------------------------------------------------
__global__ __launch_bounds__(256)
void out_gemm_k(const float* __restrict__ A, const float* __restrict__ B,
                const float* __restrict__ bias, float* __restrict__ C)
{
    __shared__ float As[8][128];
    __shared__ float Bs[8][128];
    const int tid = threadIdx.x;
    const int bm = blockIdx.x << 7;
    const int bn = blockIdx.y << 7;
    const int tx4 = (tid & 15) << 2;
    const int ty4 = (tid >> 4) << 2;

    const int arow = bm + (tid >> 1);
    const int akq  = (tid & 1) << 2;
    const int bkk  = tid >> 5;
    const int bcq  = (tid & 31) << 2;

    f4 aReg = *(const f4*)&A[(size_t)arow * MODEL + akq];
    f4 bReg = *(const f4*)&B[(size_t)bkk * MODEL + bn + bcq];

    float acc[8][8];
    #pragma unroll
    for (int i = 0; i < 8; ++i)
        #pragma unroll
        for (int j = 0; j < 8; ++j) acc[i][j] = 0.f;

    const int nsteps = MODEL / 8;
    for (int s = 0; s < nsteps; ++s) {
        __syncthreads();
        As[akq + 0][tid >> 1] = aReg[0];
        As[akq + 1][tid >> 1] = aReg[1];
        As[akq + 2][tid >> 1] = aReg[2];
        As[akq + 3][tid >> 1] = aReg[3];
        *(f4*)&Bs[bkk][bcq] = bReg;
        __syncthreads();
        if (s + 1 < nsteps) {
            const int k0 = (s + 1) << 3;
            aReg = *(const f4*)&A[(size_t)arow * MODEL + k0 + akq];
            bReg = *(const f4*)&B[(size_t)(k0 + bkk) * MODEL + bn + bcq];
        }
        #pragma unroll
        for (int kk = 0; kk < 8; ++kk) {
            f4 a0 = *(const f4*)&As[kk][ty4];
            f4 a1 = *(const f4*)&As[kk][64 + ty4];
            f4 b0 = *(const f4*)&Bs[kk][tx4];
            f4 b1 = *(const f4*)&Bs[kk][64 + tx4];
            #pragma unroll
            for (int i = 0; i < 4; ++i)
                #pragma unroll
                for (int j = 0; j < 4; ++j) {
                    acc[i][j]         += a0[i] * b0[j];
                    acc[i][j + 4]     += a0[i] * b1[j];
                    acc[i + 4][j]     += a1[i] * b0[j];
                    acc[i + 4][j + 4] += a1[i] * b1[j];
                }
        }
    }

    #pragma unroll
    for (int ii = 0; ii < 8; ++ii) {
        const int r = bm + ((ii < 4) ? (ty4 + ii) : (64 + ty4 + ii - 4));
        #pragma unroll
        for (int jj = 0; jj < 8; ++jj) {
            const int c = bn + ((jj < 4) ? (tx4 + jj) : (64 + tx4 + jj - 4));
            C[(size_t)r * MODEL + c] = acc[ii][jj] + bias[c];
        }
    }
}

extern "C" void kernel_launch(void* const* d_in, const int* in_sizes, int n_in,
                              void* d_out, int out_size, void* d_ws, size_t ws_size,
                              hipStream_t stream)
{
    const float* x     = (const float*)d_in[0];
    const float* w_qkv = (const float*)d_in[1];
    const float* w_out = (const float*)d_in[2];
    const float* b_out = (const float*)d_in[3];
    float* out = (float*)d_out;

    float* ws   = (float*)d_ws;
    float* qb   = ws;                      // [64][2048][64]
    float* kb   = qb + BUF_ELEMS;
    float* vb   = kb + BUF_ELEMS;
    float* atto = vb + BUF_ELEMS;          // [8192][1024]

    dim3 blk(256);
    qkv_gemm_k<<<dim3(MTOT / 128, NQKV / 128), blk, 0, stream>>>(x, w_qkv, qb, kb, vb);
    attn_k<<<dim3(NBAT * NH, TOK / 64), blk, 0, stream>>>(qb, kb, vb, atto);
    out_gemm_k<<<dim3(MTOT / 128, MODEL / 128), blk, 0, stream>>>(atto, w_out, b_out, out);
}

// Round 2
// 1009.743 us; speedup vs baseline: 1.9550x; 1.9550x over previous
//
#include <hip/hip_runtime.h>
#include <hip/hip_bf16.h>
#include <cmath>

typedef float f4 __attribute__((ext_vector_type(4)));
typedef float f32x4 __attribute__((ext_vector_type(4)));
typedef short bf16x8 __attribute__((ext_vector_type(8)));
typedef unsigned short us4 __attribute__((ext_vector_type(4)));

#define TOK   2048
#define NBAT  4
#define NH    16
#define DH    64
#define MODEL 1024
#define MTOT  (NBAT*TOK)          // 8192
#define NQKV  (3*MODEL)           // 3072
#define ATT_SCALE 0.125f
#define BUF_ELEMS ((size_t)MTOT*MODEL)   // 8388608 elems per q/k/v buffer

__device__ inline unsigned short f2bf(float x) {
    union { __hip_bfloat16 h; unsigned short u; } cv;
    cv.h = __float2bfloat16(x);
    return cv.u;
}

__device__ inline float rmax16(float v) {
    v = fmaxf(v, __shfl_xor(v, 1));
    v = fmaxf(v, __shfl_xor(v, 2));
    v = fmaxf(v, __shfl_xor(v, 4));
    v = fmaxf(v, __shfl_xor(v, 8));
    return v;
}
__device__ inline float rsum16(float v) {
    v += __shfl_xor(v, 1);
    v += __shfl_xor(v, 2);
    v += __shfl_xor(v, 4);
    v += __shfl_xor(v, 8);
    return v;
}

// ---------------------------------------------------------------------------
// GEMM1: x[8192][1024] @ w_qkv[1024][3072] (fp32 compute).
// Epilogue: q (pre-scaled by 0.125) and k as bf16 [bh][n][64];
//           v as bf16 TRANSPOSED [bh][d][n].
// ---------------------------------------------------------------------------
__global__ __launch_bounds__(256)
void qkv_gemm_k(const float* __restrict__ A, const float* __restrict__ B,
                unsigned short* __restrict__ qb, unsigned short* __restrict__ kb,
                unsigned short* __restrict__ vt)
{
    __shared__ float As[8][128];   // As[k][m]
    __shared__ float Bs[8][128];   // Bs[k][n]
    const int tid = threadIdx.x;
    const int bm = blockIdx.x << 7;
    const int bn = blockIdx.y << 7;
    const int tx4 = (tid & 15) << 2;
    const int ty4 = (tid >> 4) << 2;

    const int arow = bm + (tid >> 1);
    const int akq  = (tid & 1) << 2;
    const int bkk  = tid >> 5;
    const int bcq  = (tid & 31) << 2;

    f4 aReg = *(const f4*)&A[(size_t)arow * MODEL + akq];
    f4 bReg = *(const f4*)&B[(size_t)bkk * NQKV + bn + bcq];

    float acc[8][8];
    #pragma unroll
    for (int i = 0; i < 8; ++i)
        #pragma unroll
        for (int j = 0; j < 8; ++j) acc[i][j] = 0.f;

    const int nsteps = MODEL / 8;
    for (int s = 0; s < nsteps; ++s) {
        __syncthreads();
        As[akq + 0][tid >> 1] = aReg[0];
        As[akq + 1][tid >> 1] = aReg[1];
        As[akq + 2][tid >> 1] = aReg[2];
        As[akq + 3][tid >> 1] = aReg[3];
        *(f4*)&Bs[bkk][bcq] = bReg;
        __syncthreads();
        if (s + 1 < nsteps) {
            const int k0 = (s + 1) << 3;
            aReg = *(const f4*)&A[(size_t)arow * MODEL + k0 + akq];
            bReg = *(const f4*)&B[(size_t)(k0 + bkk) * NQKV + bn + bcq];
        }
        #pragma unroll
        for (int kk = 0; kk < 8; ++kk) {
            f4 a0 = *(const f4*)&As[kk][ty4];
            f4 a1 = *(const f4*)&As[kk][64 + ty4];
            f4 b0 = *(const f4*)&Bs[kk][tx4];
            f4 b1 = *(const f4*)&Bs[kk][64 + tx4];
            #pragma unroll
            for (int i = 0; i < 4; ++i)
                #pragma unroll
                for (int j = 0; j < 4; ++j) {
                    acc[i][j]         += a0[i] * b0[j];
                    acc[i][j + 4]     += a0[i] * b1[j];
                    acc[i + 4][j]     += a1[i] * b0[j];
                    acc[i + 4][j + 4] += a1[i] * b1[j];
                }
        }
    }

    // epilogue: bf16 q/k row-major, v transposed
    #pragma unroll
    for (int g = 0; g < 2; ++g) {
        const int c0  = bn + (g << 6) + tx4;     // first of 4 consecutive cols
        const int sel = c0 >> 10;
        const int cc  = c0 & 1023;
        const int h   = cc >> 6;
        const int dd  = cc & 63;
        if (sel < 2) {
            unsigned short* pq = sel ? kb : qb;
            const float mul = sel ? 1.0f : ATT_SCALE;   // pre-scale q
            #pragma unroll
            for (int ii = 0; ii < 8; ++ii) {
                const int r  = bm + ((ii < 4) ? (ty4 + ii) : (64 + ty4 + ii - 4));
                const int bb = r >> 11;
                const int nn = r & (TOK - 1);
                us4 u;
                #pragma unroll
                for (int jq = 0; jq < 4; ++jq)
                    u[jq] = f2bf(acc[ii][(g << 2) + jq] * mul);
                *(us4*)&pq[(((size_t)(bb * NH + h) * TOK) + nn) * DH + dd] = u;
            }
        } else {
            #pragma unroll
            for (int jq = 0; jq < 4; ++jq) {
                const int ddj = dd + jq;
                #pragma unroll
                for (int gr = 0; gr < 2; ++gr) {
                    const int r0 = bm + (gr << 6) + ty4;   // 4 consecutive rows
                    const int bb = r0 >> 11;
                    const int nn = r0 & (TOK - 1);
                    us4 u;
                    #pragma unroll
                    for (int iq = 0; iq < 4; ++iq)
                        u[iq] = f2bf(acc[(gr << 2) + iq][(g << 2) + jq]);
                    *(us4*)&vt[(((size_t)(bb * NH + h) * DH) + ddj) * TOK + nn] = u;
                }
            }
        }
    }
}

// ---------------------------------------------------------------------------
// MFMA flash attention. Block = (64-query tile, bh), 256 threads = 4 waves.
// Wave w owns q rows [w*16, w*16+16). K tiles of 64 keys.
// Layouts (verified m89/AMD blog): A[row=l&15][k=(l>>4)*8+i],
// B[k=(l>>4)*8+i][col=l&15], D[row=(l>>4)*4+r][col=l&15].
// ---------------------------------------------------------------------------
__global__ __launch_bounds__(256)
void attn_mfma_k(const unsigned short* __restrict__ qb,
                 const unsigned short* __restrict__ kb,
                 const unsigned short* __restrict__ vt,
                 float* __restrict__ ob)
{
    __shared__ unsigned short Qs[64][72];   // Q tile, then reused as P
    __shared__ unsigned short Ks[64][72];   // K tile row-major [key][d]
    __shared__ unsigned short Vs[64][72];   // V tile transposed [d][key]

    const int tid  = threadIdx.x;
    const int lane = tid & 63;
    const int w    = tid >> 6;          // wave 0..3
    const int l15  = lane & 15;
    const int lg   = lane >> 4;         // 0..3
    const int q0   = blockIdx.x << 6;
    const int bh   = blockIdx.y;

    const unsigned short* Q = qb + (size_t)bh * TOK * DH;
    const unsigned short* K = kb + (size_t)bh * TOK * DH;
    const unsigned short* V = vt + (size_t)bh * DH * TOK;

    // load Q tile (64x64 bf16)
    #pragma unroll
    for (int r = 0; r < 2; ++r) {
        const int c   = tid + (r << 8);
        const int row = c >> 3;
        const int off = (c & 7) << 3;
        *(bf16x8*)&Qs[row][off] = *(const bf16x8*)&Q[(size_t)(q0 + row) * DH + off];
    }
    __syncthreads();
    // hoist Q A-fragments (constant across all k-tiles)
    const bf16x8 aq0 = *(const bf16x8*)&Qs[(w << 4) + l15][lg << 3];
    const bf16x8 aq1 = *(const bf16x8*)&Qs[(w << 4) + l15][32 + (lg << 3)];
    __syncthreads();   // Qs now free for P staging

    float m_i[4], l_i[4];
    f32x4 o[4];
    #pragma unroll
    for (int r = 0; r < 4; ++r) {
        m_i[r] = -1e30f;
        l_i[r] = 0.f;
        o[r] = (f32x4){0.f, 0.f, 0.f, 0.f};
    }

    for (int kt = 0; kt < TOK / 64; ++kt) {
        const int k0 = kt << 6;
        __syncthreads();   // previous PV reads of Ks/Vs/P done
        #pragma unroll
        for (int r = 0; r < 2; ++r) {
            const int c   = tid + (r << 8);
            const int row = c >> 3;
            const int off = (c & 7) << 3;
            *(bf16x8*)&Ks[row][off] = *(const bf16x8*)&K[(size_t)(k0 + row) * DH + off];
            *(bf16x8*)&Vs[row][off] = *(const bf16x8*)&V[(size_t)row * TOK + k0 + off];
        }
        __syncthreads();

        // S = Q K^T (q pre-scaled) ; 4 col tiles x (K=64 -> 2 chained mfma)
        f32x4 s[4];
        #pragma unroll
        for (int j = 0; j < 4; ++j) {
            const bf16x8 bk0 = *(const bf16x8*)&Ks[(j << 4) + l15][lg << 3];
            const bf16x8 bk1 = *(const bf16x8*)&Ks[(j << 4) + l15][32 + (lg << 3)];
            f32x4 acc = (f32x4){0.f, 0.f, 0.f, 0.f};
            acc = __builtin_amdgcn_mfma_f32_16x16x32_bf16(aq0, bk0, acc, 0, 0, 0);
            acc = __builtin_amdgcn_mfma_f32_16x16x32_bf16(aq1, bk1, acc, 0, 0, 0);
            s[j] = acc;
        }

        // online softmax; rows = lg*4+r replicated across the 16 lanes l15
        #pragma unroll
        for (int r = 0; r < 4; ++r) {
            float rm = fmaxf(fmaxf(s[0][r], s[1][r]), fmaxf(s[2][r], s[3][r]));
            rm = rmax16(rm);
            const float mnew = fmaxf(m_i[r], rm);
            const float sf   = __expf(m_i[r] - mnew);
            float p0 = __expf(s[0][r] - mnew);
            float p1 = __expf(s[1][r] - mnew);
            float p2 = __expf(s[2][r] - mnew);
            float p3 = __expf(s[3][r] - mnew);
            const float rs = rsum16(p0 + p1 + p2 + p3);
            l_i[r] = l_i[r] * sf + rs;
            m_i[r] = mnew;
            // rescale O
            #pragma unroll
            for (int dj = 0; dj < 4; ++dj) o[dj][r] *= sf;
            // stage P (bf16) into the retired Q buffer
            const int prow = (w << 4) + (lg << 2) + r;
            Qs[prow][(0 << 4) + l15] = f2bf(p0);
            Qs[prow][(1 << 4) + l15] = f2bf(p1);
            Qs[prow][(2 << 4) + l15] = f2bf(p2);
            Qs[prow][(3 << 4) + l15] = f2bf(p3);
        }
        __syncthreads();   // P visible (also orders wave-local write->read)

        // O += P V : A = P strip, B = Vt
        const bf16x8 pa0 = *(const bf16x8*)&Qs[(w << 4) + l15][lg << 3];
        const bf16x8 pa1 = *(const bf16x8*)&Qs[(w << 4) + l15][32 + (lg << 3)];
        #pragma unroll
        for (int dj = 0; dj < 4; ++dj) {
            const bf16x8 bv0 = *(const bf16x8*)&Vs[(dj << 4) + l15][lg << 3];
            const bf16x8 bv1 = *(const bf16x8*)&Vs[(dj << 4) + l15][32 + (lg << 3)];
            o[dj] = __builtin_amdgcn_mfma_f32_16x16x32_bf16(pa0, bv0, o[dj], 0, 0, 0);
            o[dj] = __builtin_amdgcn_mfma_f32_16x16x32_bf16(pa1, bv1, o[dj], 0, 0, 0);
        }
    }

    // write [b][n][h*64+d] fp32
    const int b = bh >> 4;
    const int h = bh & 15;
    #pragma unroll
    for (int r = 0; r < 4; ++r) {
        const float inv = 1.f / l_i[r];
        const int row = q0 + (w << 4) + (lg << 2) + r;
        #pragma unroll
        for (int dj = 0; dj < 4; ++dj) {
            const int col = (h << 6) + (dj << 4) + l15;
            ob[(size_t)(b * TOK + row) * MODEL + col] = o[dj][r] * inv;
        }
    }
}

// ---------------------------------------------------------------------------
// GEMM2: attn_out[8192][1024] @ w_out[1024][1024] + b_out -> d_out (fp32)
// ---------------------------------------------------------------------------
__global__ __launch_bounds__(256)
void out_gemm_k(const float* __restrict__ A, const float* __restrict__ B,
                const float* __restrict__ bias, float* __restrict__ C)
{
    __shared__ float As[8][128];
    __shared__ float Bs[8][128];
    const int tid = threadIdx.x;
    const int bm = blockIdx.x << 7;
    const int bn = blockIdx.y << 7;
    const int tx4 = (tid & 15) << 2;
    const int ty4 = (tid >> 4) << 2;

    const int arow = bm + (tid >> 1);
    const int akq  = (tid & 1) << 2;
    const int bkk  = tid >> 5;
    const int bcq  = (tid & 31) << 2;

    f4 aReg = *(const f4*)&A[(size_t)arow * MODEL + akq];
    f4 bReg = *(const f4*)&B[(size_t)bkk * MODEL + bn + bcq];

    float acc[8][8];
    #pragma unroll
    for (int i = 0; i < 8; ++i)
        #pragma unroll
        for (int j = 0; j < 8; ++j) acc[i][j] = 0.f;

    const int nsteps = MODEL / 8;
    for (int s = 0; s < nsteps; ++s) {
        __syncthreads();
        As[akq + 0][tid >> 1] = aReg[0];
        As[akq + 1][tid >> 1] = aReg[1];
        As[akq + 2][tid >> 1] = aReg[2];
        As[akq + 3][tid >> 1] = aReg[3];
        *(f4*)&Bs[bkk][bcq] = bReg;
        __syncthreads();
        if (s + 1 < nsteps) {
            const int k0 = (s + 1) << 3;
            aReg = *(const f4*)&A[(size_t)arow * MODEL + k0 + akq];
            bReg = *(const f4*)&B[(size_t)(k0 + bkk) * MODEL + bn + bcq];
        }
        #pragma unroll
        for (int kk = 0; kk < 8; ++kk) {
            f4 a0 = *(const f4*)&As[kk][ty4];
            f4 a1 = *(const f4*)&As[kk][64 + ty4];
            f4 b0 = *(const f4*)&Bs[kk][tx4];
            f4 b1 = *(const f4*)&Bs[kk][64 + tx4];
            #pragma unroll
            for (int i = 0; i < 4; ++i)
                #pragma unroll
                for (int j = 0; j < 4; ++j) {
                    acc[i][j]         += a0[i] * b0[j];
                    acc[i][j + 4]     += a0[i] * b1[j];
                    acc[i + 4][j]     += a1[i] * b0[j];
                    acc[i + 4][j + 4] += a1[i] * b1[j];
                }
        }
    }

    #pragma unroll
    for (int ii = 0; ii < 8; ++ii) {
        const int r = bm + ((ii < 4) ? (ty4 + ii) : (64 + ty4 + ii - 4));
        #pragma unroll
        for (int jj = 0; jj < 8; ++jj) {
            const int c = bn + ((jj < 4) ? (tx4 + jj) : (64 + tx4 + jj - 4));
            C[(size_t)r * MODEL + c] = acc[ii][jj] + bias[c];
        }
    }
}

extern "C" void kernel_launch(void* const* d_in, const int* in_sizes, int n_in,
                              void* d_out, int out_size, void* d_ws, size_t ws_size,
                              hipStream_t stream)
{
    const float* x     = (const float*)d_in[0];
    const float* w_qkv = (const float*)d_in[1];
    const float* w_out = (const float*)d_in[2];
    const float* b_out = (const float*)d_in[3];
    float* out = (float*)d_out;

    unsigned short* qb = (unsigned short*)d_ws;          // [64][2048][64] bf16 (q*0.125)
    unsigned short* kb = qb + BUF_ELEMS;                 // [64][2048][64] bf16
    unsigned short* vt = kb + BUF_ELEMS;                 // [64][64][2048] bf16 (transposed)
    float* atto = (float*)(vt + BUF_ELEMS);              // [8192][1024] fp32

    dim3 blk(256);
    qkv_gemm_k<<<dim3(MTOT / 128, NQKV / 128), blk, 0, stream>>>(x, w_qkv, qb, kb, vt);
    attn_mfma_k<<<dim3(TOK / 64, NBAT * NH), blk, 0, stream>>>(qb, kb, vt, atto);
    out_gemm_k<<<dim3(MTOT / 128, MODEL / 128), blk, 0, stream>>>(atto, w_out, b_out, out);
}

// Round 3
// 342.577 us; speedup vs baseline: 5.7622x; 2.9475x over previous
//
#include <hip/hip_runtime.h>
#include <hip/hip_bf16.h>
#include <cmath>

typedef float f4 __attribute__((ext_vector_type(4)));
typedef float f32x4 __attribute__((ext_vector_type(4)));
typedef short bf16x8 __attribute__((ext_vector_type(8)));
typedef unsigned short us4 __attribute__((ext_vector_type(4)));
typedef unsigned short us;

#define TOK   2048
#define NBAT  4
#define NH    16
#define DH    64
#define MODEL 1024
#define MTOT  (NBAT*TOK)          // 8192
#define NQKV  (3*MODEL)           // 3072
#define ATT_SCALE 0.125f
#define BUF_ELEMS ((size_t)MTOT*MODEL)   // 8388608 elems

__device__ inline us f2bf(float x) {
    union { __hip_bfloat16 h; us u; } cv;
    cv.h = __float2bfloat16(x);
    return cv.u;
}

__device__ inline float rmax16(float v) {
    v = fmaxf(v, __shfl_xor(v, 1));
    v = fmaxf(v, __shfl_xor(v, 2));
    v = fmaxf(v, __shfl_xor(v, 4));
    v = fmaxf(v, __shfl_xor(v, 8));
    return v;
}
__device__ inline float rsum16(float v) {
    v += __shfl_xor(v, 1);
    v += __shfl_xor(v, 2);
    v += __shfl_xor(v, 4);
    v += __shfl_xor(v, 8);
    return v;
}

// ---------------------------------------------------------------------------
// fp32 -> bf16 elementwise convert (x). One float4 per thread.
// ---------------------------------------------------------------------------
__global__ __launch_bounds__(256)
void cvt_k(const float* __restrict__ X, us* __restrict__ Y)
{
    const size_t i = ((size_t)blockIdx.x * 256 + threadIdx.x) << 2;
    f4 v = *(const f4*)&X[i];
    us4 u;
    #pragma unroll
    for (int j = 0; j < 4; ++j) u[j] = f2bf(v[j]);
    *(us4*)&Y[i] = u;
}

// ---------------------------------------------------------------------------
// fp32 W[K][N] -> bf16 WT[N][K] (LDS-tiled transpose-convert, 64x64 tiles)
// ---------------------------------------------------------------------------
__global__ __launch_bounds__(256)
void tcvt_k(const float* __restrict__ W, us* __restrict__ WT, int K, int N)
{
    __shared__ float T[64][65];
    const int n0 = blockIdx.x << 6, k0 = blockIdx.y << 6;
    const int tid = threadIdx.x;
    const int r = tid >> 4, c4 = (tid & 15) << 2;
    #pragma unroll
    for (int i = 0; i < 4; ++i) {
        const int kr = r + (i << 4);
        *(f4*)&T[kr][c4] = *(const f4*)&W[(size_t)(k0 + kr) * N + n0 + c4];
    }
    __syncthreads();
    #pragma unroll
    for (int i = 0; i < 4; ++i) {
        const int nr = r + (i << 4);
        us4 u;
        #pragma unroll
        for (int j = 0; j < 4; ++j) u[j] = f2bf(T[c4 + j][nr]);
        *(us4*)&WT[(size_t)(n0 + nr) * K + k0 + c4] = u;
    }
}

// ---------------------------------------------------------------------------
// MFMA GEMM core macro-shape: C[128][128] = A[128][K] @ B^T[128][K]
// 256 threads = 4 waves (2x2), 4x4 16x16x32 fragments per wave, BK=64,
// LDS stride 72 (bank = 4*row + c -> 2-way, free). Register prefetch.
// ---------------------------------------------------------------------------
#define GEMM_BODY(Aptr, Bptr, KDIM)                                            \
    __shared__ us As[128][72];                                                 \
    __shared__ us Bs[128][72];                                                 \
    const int tid = threadIdx.x;                                               \
    const int lane = tid & 63;                                                 \
    const int w = tid >> 6, wr = w >> 1, wc = w & 1;                           \
    const int l15 = lane & 15, lg = lane >> 4;                                 \
    const int bm = blockIdx.x << 7, bn = blockIdx.y << 7;                      \
    int srow[4], soff[4];                                                      \
    _Pragma("unroll")                                                          \
    for (int i = 0; i < 4; ++i) {                                              \
        const int c = tid + (i << 8);                                          \
        srow[i] = c >> 3; soff[i] = (c & 7) << 3;                              \
    }                                                                          \
    const us* Ag = Aptr + (size_t)bm * (KDIM);                                 \
    const us* Bg = Bptr + (size_t)bn * (KDIM);                                 \
    bf16x8 ra[4], rb[4];                                                       \
    _Pragma("unroll")                                                          \
    for (int i = 0; i < 4; ++i) {                                              \
        ra[i] = *(const bf16x8*)&Ag[(size_t)srow[i] * (KDIM) + soff[i]];       \
        rb[i] = *(const bf16x8*)&Bg[(size_t)srow[i] * (KDIM) + soff[i]];       \
    }                                                                          \
    f32x4 acc[4][4];                                                           \
    _Pragma("unroll")                                                          \
    for (int m = 0; m < 4; ++m)                                                \
        _Pragma("unroll")                                                      \
        for (int n = 0; n < 4; ++n) acc[m][n] = (f32x4){0.f, 0.f, 0.f, 0.f};   \
    const int NS = (KDIM) / 64;                                                \
    for (int s = 0; s < NS; ++s) {                                             \
        _Pragma("unroll")                                                      \
        for (int i = 0; i < 4; ++i) {                                          \
            *(bf16x8*)&As[srow[i]][soff[i]] = ra[i];                           \
            *(bf16x8*)&Bs[srow[i]][soff[i]] = rb[i];                           \
        }                                                                      \
        __syncthreads();                                                       \
        if (s + 1 < NS) {                                                      \
            const int k0 = (s + 1) << 6;                                       \
            _Pragma("unroll")                                                  \
            for (int i = 0; i < 4; ++i) {                                      \
                ra[i] = *(const bf16x8*)&Ag[(size_t)srow[i] * (KDIM) + k0 + soff[i]]; \
                rb[i] = *(const bf16x8*)&Bg[(size_t)srow[i] * (KDIM) + k0 + soff[i]]; \
            }                                                                  \
        }                                                                      \
        _Pragma("unroll")                                                      \
        for (int kk = 0; kk < 2; ++kk) {                                       \
            bf16x8 af[4], bfr[4];                                              \
            _Pragma("unroll")                                                  \
            for (int m = 0; m < 4; ++m)                                        \
                af[m] = *(const bf16x8*)&As[(wr << 6) + (m << 4) + l15][(kk << 5) + (lg << 3)]; \
            _Pragma("unroll")                                                  \
            for (int n = 0; n < 4; ++n)                                        \
                bfr[n] = *(const bf16x8*)&Bs[(wc << 6) + (n << 4) + l15][(kk << 5) + (lg << 3)]; \
            _Pragma("unroll")                                                  \
            for (int m = 0; m < 4; ++m)                                        \
                _Pragma("unroll")                                              \
                for (int n = 0; n < 4; ++n)                                    \
                    acc[m][n] = __builtin_amdgcn_mfma_f32_16x16x32_bf16(af[m], bfr[n], acc[m][n], 0, 0, 0); \
        }                                                                      \
        __syncthreads();                                                       \
    }

// ---------------------------------------------------------------------------
// GEMM1: x_bf[8192][1024] @ wqT[3072][1024]^T. Epilogue scatters bf16 q
// (pre-scaled), k row-major [bh][n][64]; v transposed [bh][d][n].
// ---------------------------------------------------------------------------
__global__ __launch_bounds__(256)
void qkv_mfma_k(const us* __restrict__ Abf, const us* __restrict__ BT,
                us* __restrict__ qb, us* __restrict__ kb, us* __restrict__ vt)
{
    GEMM_BODY(Abf, BT, MODEL)

    const int cb  = bn + (wc << 6);
    const int sel = cb >> 10;
    const int cc0 = cb & 1023;
    const int bb  = bm >> 11;
    const int nnb = (bm & (TOK - 1)) + (wr << 6);

    if (sel < 2) {
        us* p = sel ? kb : qb;
        const float mul = sel ? 1.f : ATT_SCALE;
        #pragma unroll
        for (int n = 0; n < 4; ++n) {
            const int cc = cc0 + (n << 4) + l15;
            const int h = cc >> 6, dd = cc & 63;
            us* pp = p + ((size_t)(bb * NH + h) * TOK) * DH + dd;
            #pragma unroll
            for (int m = 0; m < 4; ++m)
                #pragma unroll
                for (int r = 0; r < 4; ++r) {
                    const int nn = nnb + (m << 4) + (lg << 2) + r;
                    pp[(size_t)nn * DH] = f2bf(acc[m][n][r] * mul);
                }
        }
    } else {
        #pragma unroll
        for (int n = 0; n < 4; ++n) {
            const int cc = cc0 + (n << 4) + l15;
            const int h = cc >> 6, dd = cc & 63;
            #pragma unroll
            for (int m = 0; m < 4; ++m) {
                const int nn = nnb + (m << 4) + (lg << 2);
                us4 u;
                #pragma unroll
                for (int r = 0; r < 4; ++r) u[r] = f2bf(acc[m][n][r]);
                *(us4*)&vt[((size_t)(bb * NH + h) * DH + dd) * TOK + nn] = u;
            }
        }
    }
}

// ---------------------------------------------------------------------------
// GEMM2: atto_bf[8192][1024] @ woT[1024][1024]^T + bias -> fp32 d_out
// ---------------------------------------------------------------------------
__global__ __launch_bounds__(256)
void out_mfma_k(const us* __restrict__ Abf, const us* __restrict__ BT,
                const float* __restrict__ bias, float* __restrict__ C)
{
    GEMM_BODY(Abf, BT, MODEL)

    #pragma unroll
    for (int n = 0; n < 4; ++n) {
        const int c = bn + (wc << 6) + (n << 4) + l15;
        const float bv = bias[c];
        #pragma unroll
        for (int m = 0; m < 4; ++m) {
            const int row = bm + (wr << 6) + (m << 4) + (lg << 2);
            #pragma unroll
            for (int r = 0; r < 4; ++r)
                C[(size_t)(row + r) * MODEL + c] = acc[m][n][r] + bv;
        }
    }
}

// ---------------------------------------------------------------------------
// MFMA flash attention (as round 2), now emitting bf16 [b][n][h*64+d].
// ---------------------------------------------------------------------------
__global__ __launch_bounds__(256)
void attn_mfma_k(const us* __restrict__ qb, const us* __restrict__ kb,
                 const us* __restrict__ vt, us* __restrict__ ob)
{
    __shared__ us Qs[64][72];   // Q tile, then reused as P
    __shared__ us Ks[64][72];   // K tile row-major [key][d]
    __shared__ us Vs[64][72];   // V tile transposed [d][key]

    const int tid  = threadIdx.x;
    const int lane = tid & 63;
    const int w    = tid >> 6;
    const int l15  = lane & 15;
    const int lg   = lane >> 4;
    const int q0   = blockIdx.x << 6;
    const int bh   = blockIdx.y;

    const us* Q = qb + (size_t)bh * TOK * DH;
    const us* K = kb + (size_t)bh * TOK * DH;
    const us* V = vt + (size_t)bh * DH * TOK;

    #pragma unroll
    for (int r = 0; r < 2; ++r) {
        const int c   = tid + (r << 8);
        const int row = c >> 3;
        const int off = (c & 7) << 3;
        *(bf16x8*)&Qs[row][off] = *(const bf16x8*)&Q[(size_t)(q0 + row) * DH + off];
    }
    __syncthreads();
    const bf16x8 aq0 = *(const bf16x8*)&Qs[(w << 4) + l15][lg << 3];
    const bf16x8 aq1 = *(const bf16x8*)&Qs[(w << 4) + l15][32 + (lg << 3)];
    __syncthreads();

    float m_i[4], l_i[4];
    f32x4 o[4];
    #pragma unroll
    for (int r = 0; r < 4; ++r) {
        m_i[r] = -1e30f;
        l_i[r] = 0.f;
        o[r] = (f32x4){0.f, 0.f, 0.f, 0.f};
    }

    for (int kt = 0; kt < TOK / 64; ++kt) {
        const int k0 = kt << 6;
        __syncthreads();
        #pragma unroll
        for (int r = 0; r < 2; ++r) {
            const int c   = tid + (r << 8);
            const int row = c >> 3;
            const int off = (c & 7) << 3;
            *(bf16x8*)&Ks[row][off] = *(const bf16x8*)&K[(size_t)(k0 + row) * DH + off];
            *(bf16x8*)&Vs[row][off] = *(const bf16x8*)&V[(size_t)row * TOK + k0 + off];
        }
        __syncthreads();

        f32x4 s[4];
        #pragma unroll
        for (int j = 0; j < 4; ++j) {
            const bf16x8 bk0 = *(const bf16x8*)&Ks[(j << 4) + l15][lg << 3];
            const bf16x8 bk1 = *(const bf16x8*)&Ks[(j << 4) + l15][32 + (lg << 3)];
            f32x4 a = (f32x4){0.f, 0.f, 0.f, 0.f};
            a = __builtin_amdgcn_mfma_f32_16x16x32_bf16(aq0, bk0, a, 0, 0, 0);
            a = __builtin_amdgcn_mfma_f32_16x16x32_bf16(aq1, bk1, a, 0, 0, 0);
            s[j] = a;
        }

        #pragma unroll
        for (int r = 0; r < 4; ++r) {
            float rm = fmaxf(fmaxf(s[0][r], s[1][r]), fmaxf(s[2][r], s[3][r]));
            rm = rmax16(rm);
            const float mnew = fmaxf(m_i[r], rm);
            const float sf   = __expf(m_i[r] - mnew);
            float p0 = __expf(s[0][r] - mnew);
            float p1 = __expf(s[1][r] - mnew);
            float p2 = __expf(s[2][r] - mnew);
            float p3 = __expf(s[3][r] - mnew);
            const float rs = rsum16(p0 + p1 + p2 + p3);
            l_i[r] = l_i[r] * sf + rs;
            m_i[r] = mnew;
            #pragma unroll
            for (int dj = 0; dj < 4; ++dj) o[dj][r] *= sf;
            const int prow = (w << 4) + (lg << 2) + r;
            Qs[prow][(0 << 4) + l15] = f2bf(p0);
            Qs[prow][(1 << 4) + l15] = f2bf(p1);
            Qs[prow][(2 << 4) + l15] = f2bf(p2);
            Qs[prow][(3 << 4) + l15] = f2bf(p3);
        }
        __syncthreads();

        const bf16x8 pa0 = *(const bf16x8*)&Qs[(w << 4) + l15][lg << 3];
        const bf16x8 pa1 = *(const bf16x8*)&Qs[(w << 4) + l15][32 + (lg << 3)];
        #pragma unroll
        for (int dj = 0; dj < 4; ++dj) {
            const bf16x8 bv0 = *(const bf16x8*)&Vs[(dj << 4) + l15][lg << 3];
            const bf16x8 bv1 = *(const bf16x8*)&Vs[(dj << 4) + l15][32 + (lg << 3)];
            o[dj] = __builtin_amdgcn_mfma_f32_16x16x32_bf16(pa0, bv0, o[dj], 0, 0, 0);
            o[dj] = __builtin_amdgcn_mfma_f32_16x16x32_bf16(pa1, bv1, o[dj], 0, 0, 0);
        }
    }

    const int b = bh >> 4;
    const int h = bh & 15;
    #pragma unroll
    for (int r = 0; r < 4; ++r) {
        const float inv = 1.f / l_i[r];
        const int row = q0 + (w << 4) + (lg << 2) + r;
        #pragma unroll
        for (int dj = 0; dj < 4; ++dj) {
            const int col = (h << 6) + (dj << 4) + l15;
            ob[(size_t)(b * TOK + row) * MODEL + col] = f2bf(o[dj][r] * inv);
        }
    }
}

extern "C" void kernel_launch(void* const* d_in, const int* in_sizes, int n_in,
                              void* d_out, int out_size, void* d_ws, size_t ws_size,
                              hipStream_t stream)
{
    const float* x     = (const float*)d_in[0];
    const float* w_qkv = (const float*)d_in[1];
    const float* w_out = (const float*)d_in[2];
    const float* b_out = (const float*)d_in[3];
    float* out = (float*)d_out;

    us* qb   = (us*)d_ws;                       // [64][2048][64] bf16 (q*0.125)
    us* kb   = qb + BUF_ELEMS;                  // [64][2048][64] bf16
    us* vt   = kb + BUF_ELEMS;                  // [64][64][2048] bf16
    us* xbf  = vt + BUF_ELEMS;                  // [8192][1024] bf16
    us* wqT  = xbf + BUF_ELEMS;                 // [3072][1024] bf16
    us* woT  = wqT + (size_t)NQKV * MODEL;      // [1024][1024] bf16
    us* atto = woT + (size_t)MODEL * MODEL;     // [8192][1024] bf16

    dim3 blk(256);
    cvt_k<<<(MTOT * MODEL) / 1024, blk, 0, stream>>>(x, xbf);
    tcvt_k<<<dim3(NQKV / 64, MODEL / 64), blk, 0, stream>>>(w_qkv, wqT, MODEL, NQKV);
    tcvt_k<<<dim3(MODEL / 64, MODEL / 64), blk, 0, stream>>>(w_out, woT, MODEL, MODEL);
    qkv_mfma_k<<<dim3(MTOT / 128, NQKV / 128), blk, 0, stream>>>(xbf, wqT, qb, kb, vt);
    attn_mfma_k<<<dim3(TOK / 64, NBAT * NH), blk, 0, stream>>>(qb, kb, vt, atto);
    out_mfma_k<<<dim3(MTOT / 128, MODEL / 128), blk, 0, stream>>>(atto, woT, b_out, out);
}

// Round 4
// 336.478 us; speedup vs baseline: 5.8667x; 1.0181x over previous
//
#include <hip/hip_runtime.h>
#include <hip/hip_bf16.h>
#include <cmath>

typedef float f4 __attribute__((ext_vector_type(4)));
typedef float f32x4 __attribute__((ext_vector_type(4)));
typedef short bf16x8 __attribute__((ext_vector_type(8)));
typedef unsigned short us4 __attribute__((ext_vector_type(4)));
typedef unsigned short us;

#define TOK   2048
#define NBAT  4
#define NH    16
#define DH    64
#define MODEL 1024
#define MTOT  (NBAT*TOK)          // 8192
#define NQKV  (3*MODEL)           // 3072
#define ATT_SCALE 0.125f
#define BUF_ELEMS ((size_t)MTOT*MODEL)   // 8388608 elems

#define LGKM0() do { asm volatile("s_waitcnt lgkmcnt(0)" ::: "memory"); \
                     __builtin_amdgcn_sched_barrier(0); } while (0)

__device__ inline us f2bf(float x) {
    union { __hip_bfloat16 h; us u; } cv;
    cv.h = __float2bfloat16(x);
    return cv.u;
}

// ---------------------------------------------------------------------------
// fp32 -> bf16 elementwise convert (x). One float4 per thread.
// ---------------------------------------------------------------------------
__global__ __launch_bounds__(256)
void cvt_k(const float* __restrict__ X, us* __restrict__ Y)
{
    const size_t i = ((size_t)blockIdx.x * 256 + threadIdx.x) << 2;
    f4 v = *(const f4*)&X[i];
    us4 u;
    #pragma unroll
    for (int j = 0; j < 4; ++j) u[j] = f2bf(v[j]);
    *(us4*)&Y[i] = u;
}

// ---------------------------------------------------------------------------
// fp32 W[K][N] -> bf16 WT[N][K] (LDS-tiled transpose-convert, 64x64 tiles)
// ---------------------------------------------------------------------------
__global__ __launch_bounds__(256)
void tcvt_k(const float* __restrict__ W, us* __restrict__ WT, int K, int N)
{
    __shared__ float T[64][65];
    const int n0 = blockIdx.x << 6, k0 = blockIdx.y << 6;
    const int tid = threadIdx.x;
    const int r = tid >> 4, c4 = (tid & 15) << 2;
    #pragma unroll
    for (int i = 0; i < 4; ++i) {
        const int kr = r + (i << 4);
        *(f4*)&T[kr][c4] = *(const f4*)&W[(size_t)(k0 + kr) * N + n0 + c4];
    }
    __syncthreads();
    #pragma unroll
    for (int i = 0; i < 4; ++i) {
        const int nr = r + (i << 4);
        us4 u;
        #pragma unroll
        for (int j = 0; j < 4; ++j) u[j] = f2bf(T[c4 + j][nr]);
        *(us4*)&WT[(size_t)(n0 + nr) * K + k0 + c4] = u;
    }
}

// ---------------------------------------------------------------------------
// MFMA GEMM core: C[128][128] = A[128][K] @ B^T[128][K]
// 256 threads = 4 waves (2x2), 4x4 16x16x32 fragments per wave, BK=64.
// ---------------------------------------------------------------------------
#define GEMM_BODY(Aptr, Bptr, KDIM)                                            \
    __shared__ us As[128][72];                                                 \
    __shared__ us Bs[128][72];                                                 \
    const int tid = threadIdx.x;                                               \
    const int lane = tid & 63;                                                 \
    const int w = tid >> 6, wr = w >> 1, wc = w & 1;                           \
    const int l15 = lane & 15, lg = lane >> 4;                                 \
    const int bm = blockIdx.x << 7, bn = blockIdx.y << 7;                      \
    int srow[4], soff[4];                                                      \
    _Pragma("unroll")                                                          \
    for (int i = 0; i < 4; ++i) {                                              \
        const int c = tid + (i << 8);                                          \
        srow[i] = c >> 3; soff[i] = (c & 7) << 3;                              \
    }                                                                          \
    const us* Ag = Aptr + (size_t)bm * (KDIM);                                 \
    const us* Bg = Bptr + (size_t)bn * (KDIM);                                 \
    bf16x8 ra[4], rb[4];                                                       \
    _Pragma("unroll")                                                          \
    for (int i = 0; i < 4; ++i) {                                              \
        ra[i] = *(const bf16x8*)&Ag[(size_t)srow[i] * (KDIM) + soff[i]];       \
        rb[i] = *(const bf16x8*)&Bg[(size_t)srow[i] * (KDIM) + soff[i]];       \
    }                                                                          \
    f32x4 acc[4][4];                                                           \
    _Pragma("unroll")                                                          \
    for (int m = 0; m < 4; ++m)                                                \
        _Pragma("unroll")                                                      \
        for (int n = 0; n < 4; ++n) acc[m][n] = (f32x4){0.f, 0.f, 0.f, 0.f};   \
    const int NS = (KDIM) / 64;                                                \
    for (int s = 0; s < NS; ++s) {                                             \
        _Pragma("unroll")                                                      \
        for (int i = 0; i < 4; ++i) {                                          \
            *(bf16x8*)&As[srow[i]][soff[i]] = ra[i];                           \
            *(bf16x8*)&Bs[srow[i]][soff[i]] = rb[i];                           \
        }                                                                      \
        __syncthreads();                                                       \
        if (s + 1 < NS) {                                                      \
            const int k0 = (s + 1) << 6;                                       \
            _Pragma("unroll")                                                  \
            for (int i = 0; i < 4; ++i) {                                      \
                ra[i] = *(const bf16x8*)&Ag[(size_t)srow[i] * (KDIM) + k0 + soff[i]]; \
                rb[i] = *(const bf16x8*)&Bg[(size_t)srow[i] * (KDIM) + k0 + soff[i]]; \
            }                                                                  \
        }                                                                      \
        _Pragma("unroll")                                                      \
        for (int kk = 0; kk < 2; ++kk) {                                       \
            bf16x8 af[4], bfr[4];                                              \
            _Pragma("unroll")                                                  \
            for (int m = 0; m < 4; ++m)                                        \
                af[m] = *(const bf16x8*)&As[(wr << 6) + (m << 4) + l15][(kk << 5) + (lg << 3)]; \
            _Pragma("unroll")                                                  \
            for (int n = 0; n < 4; ++n)                                        \
                bfr[n] = *(const bf16x8*)&Bs[(wc << 6) + (n << 4) + l15][(kk << 5) + (lg << 3)]; \
            _Pragma("unroll")                                                  \
            for (int m = 0; m < 4; ++m)                                        \
                _Pragma("unroll")                                              \
                for (int n = 0; n < 4; ++n)                                    \
                    acc[m][n] = __builtin_amdgcn_mfma_f32_16x16x32_bf16(af[m], bfr[n], acc[m][n], 0, 0, 0); \
        }                                                                      \
        __syncthreads();                                                       \
    }

// ---------------------------------------------------------------------------
// GEMM1: x_bf[8192][1024] @ wqT[3072][1024]^T -> bf16 q (pre-scaled), k
// row-major [bh][n][64]; v transposed [bh][d][n].
// ---------------------------------------------------------------------------
__global__ __launch_bounds__(256)
void qkv_mfma_k(const us* __restrict__ Abf, const us* __restrict__ BT,
                us* __restrict__ qb, us* __restrict__ kb, us* __restrict__ vt)
{
    GEMM_BODY(Abf, BT, MODEL)

    const int cb  = bn + (wc << 6);
    const int sel = cb >> 10;
    const int cc0 = cb & 1023;
    const int bb  = bm >> 11;
    const int nnb = (bm & (TOK - 1)) + (wr << 6);

    if (sel < 2) {
        us* p = sel ? kb : qb;
        const float mul = sel ? 1.f : ATT_SCALE;
        #pragma unroll
        for (int n = 0; n < 4; ++n) {
            const int cc = cc0 + (n << 4) + l15;
            const int h = cc >> 6, dd = cc & 63;
            us* pp = p + ((size_t)(bb * NH + h) * TOK) * DH + dd;
            #pragma unroll
            for (int m = 0; m < 4; ++m)
                #pragma unroll
                for (int r = 0; r < 4; ++r) {
                    const int nn = nnb + (m << 4) + (lg << 2) + r;
                    pp[(size_t)nn * DH] = f2bf(acc[m][n][r] * mul);
                }
        }
    } else {
        #pragma unroll
        for (int n = 0; n < 4; ++n) {
            const int cc = cc0 + (n << 4) + l15;
            const int h = cc >> 6, dd = cc & 63;
            #pragma unroll
            for (int m = 0; m < 4; ++m) {
                const int nn = nnb + (m << 4) + (lg << 2);
                us4 u;
                #pragma unroll
                for (int r = 0; r < 4; ++r) u[r] = f2bf(acc[m][n][r]);
                *(us4*)&vt[((size_t)(bb * NH + h) * DH + dd) * TOK + nn] = u;
            }
        }
    }
}

// ---------------------------------------------------------------------------
// GEMM2: atto_bf[8192][1024] @ woT[1024][1024]^T + bias -> fp32 d_out
// ---------------------------------------------------------------------------
__global__ __launch_bounds__(256)
void out_mfma_k(const us* __restrict__ Abf, const us* __restrict__ BT,
                const float* __restrict__ bias, float* __restrict__ C)
{
    GEMM_BODY(Abf, BT, MODEL)

    #pragma unroll
    for (int n = 0; n < 4; ++n) {
        const int c = bn + (wc << 6) + (n << 4) + l15;
        const float bv = bias[c];
        #pragma unroll
        for (int m = 0; m < 4; ++m) {
            const int row = bm + (wr << 6) + (m << 4) + (lg << 2);
            #pragma unroll
            for (int r = 0; r < 4; ++r)
                C[(size_t)(row + r) * MODEL + c] = acc[m][n][r] + bv;
        }
    }
}

// ---------------------------------------------------------------------------
// Barrier-free swapped-operand flash attention.
// Block = 4 independent waves; wave owns 32 queries (2 qsets of 16).
// All MFMA fragments loaded directly from global (K/V are L1/L2/L3-resident).
// QK^T swapped: S^T = mfma(K_frag, Q_frag)  -> lane owns ONE query (col=l15),
//   16 key-values in regs -> softmax reduce = in-reg fmax/add + 2 shuffles.
// P goes through a per-wave LDS scratch (b64 writes / b128 reads, lgkmcnt
//   fence only - NO __syncthreads anywhere).
// PV swapped: O^T = mfma(Vt_frag, P_frag) -> rescale + 1/l are lane-local.
// ---------------------------------------------------------------------------
__global__ __launch_bounds__(256)
void attn2_k(const us* __restrict__ qb, const us* __restrict__ kb,
             const us* __restrict__ vt, us* __restrict__ ob)
{
    __shared__ __align__(16) us Ps[4][16][72];   // per-wave P scratch [q][key]

    const int tid  = threadIdx.x;
    const int lane = tid & 63;
    const int w    = tid >> 6;
    const int l15  = lane & 15;
    const int lg   = lane >> 4;
    const int bh   = blockIdx.y;
    const int qw   = (blockIdx.x << 7) + (w << 5);   // wave's 32-query strip

    const us* Q = qb + (size_t)bh * TOK * DH;
    const us* K = kb + (size_t)bh * TOK * DH;
    const us* V = vt + (size_t)bh * DH * TOK;

    // Hoist Q B-fragments: B[k=d][col=q=l15] = Q[q][d] contiguous
    bf16x8 qf[2][2];
    #pragma unroll
    for (int qs = 0; qs < 2; ++qs)
        #pragma unroll
        for (int h = 0; h < 2; ++h)
            qf[qs][h] = *(const bf16x8*)&Q[(size_t)(qw + (qs << 4) + l15) * DH + (h << 5) + (lg << 3)];

    float m[2] = {-1e30f, -1e30f}, l[2] = {0.f, 0.f};
    f32x4 o[2][4];
    #pragma unroll
    for (int qs = 0; qs < 2; ++qs)
        #pragma unroll
        for (int dj = 0; dj < 4; ++dj) o[qs][dj] = (f32x4){0.f, 0.f, 0.f, 0.f};

    for (int kt = 0; kt < TOK / 64; ++kt) {
        const int k0 = kt << 6;

        // K A-fragments: A[row=key=l15][k=d] = K[key][d] contiguous
        bf16x8 kf[4][2];
        #pragma unroll
        for (int j = 0; j < 4; ++j)
            #pragma unroll
            for (int h = 0; h < 2; ++h)
                kf[j][h] = *(const bf16x8*)&K[(size_t)(k0 + (j << 4) + l15) * DH + (h << 5) + (lg << 3)];

        // S^T[key][q]: rows = key-in-j (lg*4+r), col = q (l15)
        f32x4 st[2][4];
        #pragma unroll
        for (int qs = 0; qs < 2; ++qs)
            #pragma unroll
            for (int j = 0; j < 4; ++j) {
                f32x4 a = (f32x4){0.f, 0.f, 0.f, 0.f};
                a = __builtin_amdgcn_mfma_f32_16x16x32_bf16(kf[j][0], qf[qs][0], a, 0, 0, 0);
                a = __builtin_amdgcn_mfma_f32_16x16x32_bf16(kf[j][1], qf[qs][1], a, 0, 0, 0);
                st[qs][j] = a;
            }

        // V^T A-fragments (shared by both qsets): A[row=d=l15][k=key]
        bf16x8 vf[4][2];
        #pragma unroll
        for (int dj = 0; dj < 4; ++dj)
            #pragma unroll
            for (int h = 0; h < 2; ++h)
                vf[dj][h] = *(const bf16x8*)&V[(size_t)((dj << 4) + l15) * TOK + k0 + (h << 5) + (lg << 3)];

        #pragma unroll
        for (int qs = 0; qs < 2; ++qs) {
            // online softmax for this lane's query (l15); keys 16j+4lg+r in regs
            float tm = st[qs][0][0];
            #pragma unroll
            for (int j = 0; j < 4; ++j)
                #pragma unroll
                for (int r = 0; r < 4; ++r) tm = fmaxf(tm, st[qs][j][r]);
            tm = fmaxf(tm, __shfl_xor(tm, 16));
            tm = fmaxf(tm, __shfl_xor(tm, 32));
            const float mnew = fmaxf(m[qs], tm);
            const float sf = __expf(m[qs] - mnew);
            float p[4][4];
            float ts = 0.f;
            #pragma unroll
            for (int j = 0; j < 4; ++j)
                #pragma unroll
                for (int r = 0; r < 4; ++r) {
                    p[j][r] = __expf(st[qs][j][r] - mnew);
                    ts += p[j][r];
                }
            ts += __shfl_xor(ts, 16);
            ts += __shfl_xor(ts, 32);
            l[qs] = l[qs] * sf + ts;
            m[qs] = mnew;
            #pragma unroll
            for (int dj = 0; dj < 4; ++dj) o[qs][dj] *= sf;

            // stage P[q=l15][key]: 4x b64 writes (cols 16j+4lg+0..3)
            #pragma unroll
            for (int j = 0; j < 4; ++j) {
                us4 u = {f2bf(p[j][0]), f2bf(p[j][1]), f2bf(p[j][2]), f2bf(p[j][3])};
                *(us4*)&Ps[w][l15][(j << 4) + (lg << 2)] = u;
            }
            LGKM0();   // wave-local: writes visible to cross-lane reads

            // P B-fragments: B[k=key][col=q=l15] = Ps[l15][key] contiguous
            const bf16x8 pf0 = *(const bf16x8*)&Ps[w][l15][lg << 3];
            const bf16x8 pf1 = *(const bf16x8*)&Ps[w][l15][32 + (lg << 3)];

            // O^T += V^T P : rows = d-in-dj (lg*4+r), col = q (l15)
            #pragma unroll
            for (int dj = 0; dj < 4; ++dj) {
                o[qs][dj] = __builtin_amdgcn_mfma_f32_16x16x32_bf16(vf[dj][0], pf0, o[qs][dj], 0, 0, 0);
                o[qs][dj] = __builtin_amdgcn_mfma_f32_16x16x32_bf16(vf[dj][1], pf1, o[qs][dj], 0, 0, 0);
            }
            LGKM0();   // drain P reads before next qset/tile overwrites Ps
        }
    }

    // write bf16 [b][n][h*64+d]; lane owns query l15, d = 16*dj + 4*lg + r
    const int b = bh >> 4;
    const int hh = bh & 15;
    #pragma unroll
    for (int qs = 0; qs < 2; ++qs) {
        const int q = qw + (qs << 4) + l15;
        const float inv = 1.f / l[qs];
        #pragma unroll
        for (int dj = 0; dj < 4; ++dj) {
            us4 u;
            #pragma unroll
            for (int r = 0; r < 4; ++r) u[r] = f2bf(o[qs][dj][r] * inv);
            *(us4*)&ob[(size_t)(b * TOK + q) * MODEL + (hh << 6) + (dj << 4) + (lg << 2)] = u;
        }
    }
}

extern "C" void kernel_launch(void* const* d_in, const int* in_sizes, int n_in,
                              void* d_out, int out_size, void* d_ws, size_t ws_size,
                              hipStream_t stream)
{
    const float* x     = (const float*)d_in[0];
    const float* w_qkv = (const float*)d_in[1];
    const float* w_out = (const float*)d_in[2];
    const float* b_out = (const float*)d_in[3];
    float* out = (float*)d_out;

    us* qb   = (us*)d_ws;                       // [64][2048][64] bf16 (q*0.125)
    us* kb   = qb + BUF_ELEMS;                  // [64][2048][64] bf16
    us* vt   = kb + BUF_ELEMS;                  // [64][64][2048] bf16
    us* xbf  = vt + BUF_ELEMS;                  // [8192][1024] bf16
    us* wqT  = xbf + BUF_ELEMS;                 // [3072][1024] bf16
    us* woT  = wqT + (size_t)NQKV * MODEL;      // [1024][1024] bf16
    us* atto = woT + (size_t)MODEL * MODEL;     // [8192][1024] bf16

    dim3 blk(256);
    cvt_k<<<(MTOT * MODEL) / 1024, blk, 0, stream>>>(x, xbf);
    tcvt_k<<<dim3(NQKV / 64, MODEL / 64), blk, 0, stream>>>(w_qkv, wqT, MODEL, NQKV);
    tcvt_k<<<dim3(MODEL / 64, MODEL / 64), blk, 0, stream>>>(w_out, woT, MODEL, MODEL);
    qkv_mfma_k<<<dim3(MTOT / 128, NQKV / 128), blk, 0, stream>>>(xbf, wqT, qb, kb, vt);
    attn2_k<<<dim3(TOK / 128, NBAT * NH), blk, 0, stream>>>(qb, kb, vt, atto);
    out_mfma_k<<<dim3(MTOT / 128, MODEL / 128), blk, 0, stream>>>(atto, woT, b_out, out);
}

// Round 5
// 240.014 us; speedup vs baseline: 8.2246x; 1.4019x over previous
//
#include <hip/hip_runtime.h>
#include <hip/hip_bf16.h>
#include <cmath>

typedef float f4 __attribute__((ext_vector_type(4)));
typedef float f32x4 __attribute__((ext_vector_type(4)));
typedef short bf16x8 __attribute__((ext_vector_type(8)));
typedef unsigned short us4 __attribute__((ext_vector_type(4)));
typedef unsigned short us;

#define TOK   2048
#define NBAT  4
#define NH    16
#define DH    64
#define MODEL 1024
#define MTOT  (NBAT*TOK)          // 8192
#define NQKV  (3*MODEL)           // 3072
#define ATT_SCALE 0.125f
#define BUF_ELEMS ((size_t)MTOT*MODEL)   // 8388608 elems

__device__ inline us f2bf(float x) {
    union { __hip_bfloat16 h; us u; } cv;
    cv.h = __float2bfloat16(x);
    return cv.u;
}

// ---------------------------------------------------------------------------
// fp32 -> bf16 elementwise convert (x). One float4 per thread.
// ---------------------------------------------------------------------------
__global__ __launch_bounds__(256)
void cvt_k(const float* __restrict__ X, us* __restrict__ Y)
{
    const size_t i = ((size_t)blockIdx.x * 256 + threadIdx.x) << 2;
    f4 v = *(const f4*)&X[i];
    us4 u;
    #pragma unroll
    for (int j = 0; j < 4; ++j) u[j] = f2bf(v[j]);
    *(us4*)&Y[i] = u;
}

// ---------------------------------------------------------------------------
// fp32 W[K][N] -> bf16 WT[N][K] (LDS-tiled transpose-convert, 64x64 tiles)
// ---------------------------------------------------------------------------
__global__ __launch_bounds__(256)
void tcvt_k(const float* __restrict__ W, us* __restrict__ WT, int K, int N)
{
    __shared__ float T[64][65];
    const int n0 = blockIdx.x << 6, k0 = blockIdx.y << 6;
    const int tid = threadIdx.x;
    const int r = tid >> 4, c4 = (tid & 15) << 2;
    #pragma unroll
    for (int i = 0; i < 4; ++i) {
        const int kr = r + (i << 4);
        *(f4*)&T[kr][c4] = *(const f4*)&W[(size_t)(k0 + kr) * N + n0 + c4];
    }
    __syncthreads();
    #pragma unroll
    for (int i = 0; i < 4; ++i) {
        const int nr = r + (i << 4);
        us4 u;
        #pragma unroll
        for (int j = 0; j < 4; ++j) u[j] = f2bf(T[c4 + j][nr]);
        *(us4*)&WT[(size_t)(n0 + nr) * K + k0 + c4] = u;
    }
}

// ---------------------------------------------------------------------------
// MFMA GEMM core: C[128][128] = A[128][K] @ B^T[128][K]
// 256 threads = 4 waves (2x2), 4x4 16x16x32 fragments per wave, BK=64.
// ---------------------------------------------------------------------------
#define GEMM_BODY(Aptr, Bptr, KDIM)                                            \
    __shared__ us As[128][72];                                                 \
    __shared__ us Bs[128][72];                                                 \
    const int tid = threadIdx.x;                                               \
    const int lane = tid & 63;                                                 \
    const int w = tid >> 6, wr = w >> 1, wc = w & 1;                           \
    const int l15 = lane & 15, lg = lane >> 4;                                 \
    const int bm = blockIdx.x << 7, bn = blockIdx.y << 7;                      \
    int srow[4], soff[4];                                                      \
    _Pragma("unroll")                                                          \
    for (int i = 0; i < 4; ++i) {                                              \
        const int c = tid + (i << 8);                                          \
        srow[i] = c >> 3; soff[i] = (c & 7) << 3;                              \
    }                                                                          \
    const us* Ag = Aptr + (size_t)bm * (KDIM);                                 \
    const us* Bg = Bptr + (size_t)bn * (KDIM);                                 \
    bf16x8 ra[4], rb[4];                                                       \
    _Pragma("unroll")                                                          \
    for (int i = 0; i < 4; ++i) {                                              \
        ra[i] = *(const bf16x8*)&Ag[(size_t)srow[i] * (KDIM) + soff[i]];       \
        rb[i] = *(const bf16x8*)&Bg[(size_t)srow[i] * (KDIM) + soff[i]];       \
    }                                                                          \
    f32x4 acc[4][4];                                                           \
    _Pragma("unroll")                                                          \
    for (int m = 0; m < 4; ++m)                                                \
        _Pragma("unroll")                                                      \
        for (int n = 0; n < 4; ++n) acc[m][n] = (f32x4){0.f, 0.f, 0.f, 0.f};   \
    const int NS = (KDIM) / 64;                                                \
    for (int s = 0; s < NS; ++s) {                                             \
        _Pragma("unroll")                                                      \
        for (int i = 0; i < 4; ++i) {                                          \
            *(bf16x8*)&As[srow[i]][soff[i]] = ra[i];                           \
            *(bf16x8*)&Bs[srow[i]][soff[i]] = rb[i];                           \
        }                                                                      \
        __syncthreads();                                                       \
        if (s + 1 < NS) {                                                      \
            const int k0 = (s + 1) << 6;                                       \
            _Pragma("unroll")                                                  \
            for (int i = 0; i < 4; ++i) {                                      \
                ra[i] = *(const bf16x8*)&Ag[(size_t)srow[i] * (KDIM) + k0 + soff[i]]; \
                rb[i] = *(const bf16x8*)&Bg[(size_t)srow[i] * (KDIM) + k0 + soff[i]]; \
            }                                                                  \
        }                                                                      \
        _Pragma("unroll")                                                      \
        for (int kk = 0; kk < 2; ++kk) {                                       \
            bf16x8 af[4], bfr[4];                                              \
            _Pragma("unroll")                                                  \
            for (int m = 0; m < 4; ++m)                                        \
                af[m] = *(const bf16x8*)&As[(wr << 6) + (m << 4) + l15][(kk << 5) + (lg << 3)]; \
            _Pragma("unroll")                                                  \
            for (int n = 0; n < 4; ++n)                                        \
                bfr[n] = *(const bf16x8*)&Bs[(wc << 6) + (n << 4) + l15][(kk << 5) + (lg << 3)]; \
            _Pragma("unroll")                                                  \
            for (int m = 0; m < 4; ++m)                                        \
                _Pragma("unroll")                                              \
                for (int n = 0; n < 4; ++n)                                    \
                    acc[m][n] = __builtin_amdgcn_mfma_f32_16x16x32_bf16(af[m], bfr[n], acc[m][n], 0, 0, 0); \
        }                                                                      \
        __syncthreads();                                                       \
    }

// ---------------------------------------------------------------------------
// GEMM1: x_bf[8192][1024] @ wqT[3072][1024]^T -> bf16 q (pre-scaled), k
// row-major [bh][n][64]; v transposed [bh][d][n].
// ---------------------------------------------------------------------------
__global__ __launch_bounds__(256)
void qkv_mfma_k(const us* __restrict__ Abf, const us* __restrict__ BT,
                us* __restrict__ qb, us* __restrict__ kb, us* __restrict__ vt)
{
    GEMM_BODY(Abf, BT, MODEL)

    const int cb  = bn + (wc << 6);
    const int sel = cb >> 10;
    const int cc0 = cb & 1023;
    const int bb  = bm >> 11;
    const int nnb = (bm & (TOK - 1)) + (wr << 6);

    if (sel < 2) {
        us* p = sel ? kb : qb;
        const float mul = sel ? 1.f : ATT_SCALE;
        #pragma unroll
        for (int n = 0; n < 4; ++n) {
            const int cc = cc0 + (n << 4) + l15;
            const int h = cc >> 6, dd = cc & 63;
            us* pp = p + ((size_t)(bb * NH + h) * TOK) * DH + dd;
            #pragma unroll
            for (int m = 0; m < 4; ++m)
                #pragma unroll
                for (int r = 0; r < 4; ++r) {
                    const int nn = nnb + (m << 4) + (lg << 2) + r;
                    pp[(size_t)nn * DH] = f2bf(acc[m][n][r] * mul);
                }
        }
    } else {
        #pragma unroll
        for (int n = 0; n < 4; ++n) {
            const int cc = cc0 + (n << 4) + l15;
            const int h = cc >> 6, dd = cc & 63;
            #pragma unroll
            for (int m = 0; m < 4; ++m) {
                const int nn = nnb + (m << 4) + (lg << 2);
                us4 u;
                #pragma unroll
                for (int r = 0; r < 4; ++r) u[r] = f2bf(acc[m][n][r]);
                *(us4*)&vt[((size_t)(bb * NH + h) * DH + dd) * TOK + nn] = u;
            }
        }
    }
}

// ---------------------------------------------------------------------------
// GEMM2: atto_bf[8192][1024] @ woT[1024][1024]^T + bias -> fp32 d_out
// ---------------------------------------------------------------------------
__global__ __launch_bounds__(256)
void out_mfma_k(const us* __restrict__ Abf, const us* __restrict__ BT,
                const float* __restrict__ bias, float* __restrict__ C)
{
    GEMM_BODY(Abf, BT, MODEL)

    #pragma unroll
    for (int n = 0; n < 4; ++n) {
        const int c = bn + (wc << 6) + (n << 4) + l15;
        const float bv = bias[c];
        #pragma unroll
        for (int m = 0; m < 4; ++m) {
            const int row = bm + (wr << 6) + (m << 4) + (lg << 2);
            #pragma unroll
            for (int r = 0; r < 4; ++r)
                C[(size_t)(row + r) * MODEL + c] = acc[m][n][r] + bv;
        }
    }
}

// ---------------------------------------------------------------------------
// LDS-staged swapped-operand flash attention (T2 + T14 + T5).
// Block = 4 waves x 32 q = 128 queries. K/V tiles [64][64] bf16 double-
// buffered in LDS with 16B-chunk XOR swizzle (chunk ^= row&7) so the
// stride-128B fragment reads are bank-conflict-free. Staging is reg-split:
// global->reg issued BEFORE the tile barrier, ds_write AFTER compute, so
// HBM/L2 latency hides under the previous tile's MFMA+softmax.
// Swapped QK^T: S^T = mfma(K,Q), lane owns one q (col=l15); softmax in-reg
// + 2 shuffles; P via per-wave LDS scratch (in-order DS, no fences).
// Swapped PV: O^T = mfma(V^T,P); rescale and 1/l lane-local.
// ---------------------------------------------------------------------------
__global__ __launch_bounds__(256)
void attn3_k(const us* __restrict__ qb, const us* __restrict__ kb,
             const us* __restrict__ vt, us* __restrict__ ob)
{
    __shared__ __align__(16) us Ks[2][64 * 64];    // [buf][key][d] swizzled
    __shared__ __align__(16) us Vs[2][64 * 64];    // [buf][d][key] swizzled
    __shared__ __align__(16) us Ps[4][16][72];     // per-wave P scratch

    const int tid  = threadIdx.x;
    const int lane = tid & 63;
    const int w    = tid >> 6;
    const int l15  = lane & 15;
    const int lg   = lane >> 4;
    const int bh   = blockIdx.y;
    const int qw   = (blockIdx.x << 7) + (w << 5);   // wave's 32-query strip

    const us* Q = qb + (size_t)bh * TOK * DH;
    const us* K = kb + (size_t)bh * TOK * DH;
    const us* V = vt + (size_t)bh * DH * TOK;

    // staging geometry: thread covers 16B chunks (tid) and (tid+256) per tile
    int sr[2], sc[2], sl[2];
    #pragma unroll
    for (int i = 0; i < 2; ++i) {
        const int idx = tid + (i << 8);
        sr[i] = idx >> 3;                    // row (key for K, d for V)
        sc[i] = idx & 7;                     // linear chunk in row
        sl[i] = sr[i] * 64 + ((sc[i] ^ (sr[i] & 7)) << 3);  // swizzled LDS elem
    }

    // fragment-read swizzled chunk offsets (elems), h = 0,1
    const int cs0 = (((0 << 2) + lg) ^ (l15 & 7)) << 3;
    const int cs1 = (((1 << 2) + lg) ^ (l15 & 7)) << 3;

    // hoist Q B-fragments: B[k=d][col=q=l15]
    bf16x8 qf[2][2];
    #pragma unroll
    for (int qs = 0; qs < 2; ++qs)
        #pragma unroll
        for (int h = 0; h < 2; ++h)
            qf[qs][h] = *(const bf16x8*)&Q[(size_t)(qw + (qs << 4) + l15) * DH + (h << 5) + (lg << 3)];

    float m[2] = {-1e30f, -1e30f}, l[2] = {0.f, 0.f};
    f32x4 o[2][4];
    #pragma unroll
    for (int qs = 0; qs < 2; ++qs)
        #pragma unroll
        for (int dj = 0; dj < 4; ++dj) o[qs][dj] = (f32x4){0.f, 0.f, 0.f, 0.f};

    const int NT = TOK / 64;
    bf16x8 krg[2], vrg[2];

    // prologue: stage tile 0
    #pragma unroll
    for (int i = 0; i < 2; ++i) {
        krg[i] = *(const bf16x8*)&K[(size_t)sr[i] * DH + (sc[i] << 3)];
        vrg[i] = *(const bf16x8*)&V[(size_t)sr[i] * TOK + (sc[i] << 3)];
    }
    #pragma unroll
    for (int i = 0; i < 2; ++i) {
        *(bf16x8*)&Ks[0][sl[i]] = krg[i];
        *(bf16x8*)&Vs[0][sl[i]] = vrg[i];
    }

    int cur = 0;
    for (int t = 0; t < NT; ++t) {
        // issue next tile's global loads (latency hides under this tile)
        if (t + 1 < NT) {
            const int k0 = (t + 1) << 6;
            #pragma unroll
            for (int i = 0; i < 2; ++i) {
                krg[i] = *(const bf16x8*)&K[(size_t)(k0 + sr[i]) * DH + (sc[i] << 3)];
                vrg[i] = *(const bf16x8*)&V[(size_t)sr[i] * TOK + k0 + (sc[i] << 3)];
            }
        }
        __syncthreads();   // buf[cur] writes visible; prior reads of buf[cur^1] done

        // V^T fragments held for both qsets: A[row=d=l15][k=key]
        bf16x8 vf[4][2];
        #pragma unroll
        for (int dj = 0; dj < 4; ++dj) {
            vf[dj][0] = *(const bf16x8*)&Vs[cur][((dj << 4) + l15) * 64 + cs0];
            vf[dj][1] = *(const bf16x8*)&Vs[cur][((dj << 4) + l15) * 64 + cs1];
        }

        #pragma unroll
        for (int qs = 0; qs < 2; ++qs) {
            // S^T = K Q : A[row=key=l15][k=d]
            f32x4 st[4];
            __builtin_amdgcn_s_setprio(1);
            #pragma unroll
            for (int j = 0; j < 4; ++j) {
                const bf16x8 kf0 = *(const bf16x8*)&Ks[cur][((j << 4) + l15) * 64 + cs0];
                const bf16x8 kf1 = *(const bf16x8*)&Ks[cur][((j << 4) + l15) * 64 + cs1];
                f32x4 a = (f32x4){0.f, 0.f, 0.f, 0.f};
                a = __builtin_amdgcn_mfma_f32_16x16x32_bf16(kf0, qf[qs][0], a, 0, 0, 0);
                a = __builtin_amdgcn_mfma_f32_16x16x32_bf16(kf1, qf[qs][1], a, 0, 0, 0);
                st[j] = a;
            }
            __builtin_amdgcn_s_setprio(0);

            // online softmax for lane's query (col=l15); 16 keys in regs
            float tm = st[0][0];
            #pragma unroll
            for (int j = 0; j < 4; ++j)
                #pragma unroll
                for (int r = 0; r < 4; ++r) tm = fmaxf(tm, st[j][r]);
            tm = fmaxf(tm, __shfl_xor(tm, 16));
            tm = fmaxf(tm, __shfl_xor(tm, 32));
            const float mnew = fmaxf(m[qs], tm);
            const float sf = __expf(m[qs] - mnew);
            float p[4][4];
            float ts = 0.f;
            #pragma unroll
            for (int j = 0; j < 4; ++j)
                #pragma unroll
                for (int r = 0; r < 4; ++r) {
                    p[j][r] = __expf(st[j][r] - mnew);
                    ts += p[j][r];
                }
            ts += __shfl_xor(ts, 16);
            ts += __shfl_xor(ts, 32);
            l[qs] = l[qs] * sf + ts;
            m[qs] = mnew;
            #pragma unroll
            for (int dj = 0; dj < 4; ++dj) o[qs][dj] *= sf;

            // stage P[q=l15][key] (wave-local; in-order DS, no fences)
            #pragma unroll
            for (int j = 0; j < 4; ++j) {
                us4 u = {f2bf(p[j][0]), f2bf(p[j][1]), f2bf(p[j][2]), f2bf(p[j][3])};
                *(us4*)&Ps[w][l15][(j << 4) + (lg << 2)] = u;
            }
            const bf16x8 pf0 = *(const bf16x8*)&Ps[w][l15][lg << 3];
            const bf16x8 pf1 = *(const bf16x8*)&Ps[w][l15][32 + (lg << 3)];

            // O^T += V^T P
            __builtin_amdgcn_s_setprio(1);
            #pragma unroll
            for (int dj = 0; dj < 4; ++dj) {
                o[qs][dj] = __builtin_amdgcn_mfma_f32_16x16x32_bf16(vf[dj][0], pf0, o[qs][dj], 0, 0, 0);
                o[qs][dj] = __builtin_amdgcn_mfma_f32_16x16x32_bf16(vf[dj][1], pf1, o[qs][dj], 0, 0, 0);
            }
            __builtin_amdgcn_s_setprio(0);
        }

        // write staged regs into the other buffer (after this tile's reads)
        if (t + 1 < NT) {
            #pragma unroll
            for (int i = 0; i < 2; ++i) {
                *(bf16x8*)&Ks[cur ^ 1][sl[i]] = krg[i];
                *(bf16x8*)&Vs[cur ^ 1][sl[i]] = vrg[i];
            }
        }
        cur ^= 1;
    }

    // write bf16 [b][n][h*64+d]; lane owns query l15, d = 16*dj + 4*lg + r
    const int b = bh >> 4;
    const int hh = bh & 15;
    #pragma unroll
    for (int qs = 0; qs < 2; ++qs) {
        const int q = qw + (qs << 4) + l15;
        const float inv = 1.f / l[qs];
        #pragma unroll
        for (int dj = 0; dj < 4; ++dj) {
            us4 u;
            #pragma unroll
            for (int r = 0; r < 4; ++r) u[r] = f2bf(o[qs][dj][r] * inv);
            *(us4*)&ob[(size_t)(b * TOK + q) * MODEL + (hh << 6) + (dj << 4) + (lg << 2)] = u;
        }
    }
}

extern "C" void kernel_launch(void* const* d_in, const int* in_sizes, int n_in,
                              void* d_out, int out_size, void* d_ws, size_t ws_size,
                              hipStream_t stream)
{
    const float* x     = (const float*)d_in[0];
    const float* w_qkv = (const float*)d_in[1];
    const float* w_out = (const float*)d_in[2];
    const float* b_out = (const float*)d_in[3];
    float* out = (float*)d_out;

    us* qb   = (us*)d_ws;                       // [64][2048][64] bf16 (q*0.125)
    us* kb   = qb + BUF_ELEMS;                  // [64][2048][64] bf16
    us* vt   = kb + BUF_ELEMS;                  // [64][64][2048] bf16
    us* xbf  = vt + BUF_ELEMS;                  // [8192][1024] bf16
    us* wqT  = xbf + BUF_ELEMS;                 // [3072][1024] bf16
    us* woT  = wqT + (size_t)NQKV * MODEL;      // [1024][1024] bf16
    us* atto = woT + (size_t)MODEL * MODEL;     // [8192][1024] bf16

    dim3 blk(256);
    cvt_k<<<(MTOT * MODEL) / 1024, blk, 0, stream>>>(x, xbf);
    tcvt_k<<<dim3(NQKV / 64, MODEL / 64), blk, 0, stream>>>(w_qkv, wqT, MODEL, NQKV);
    tcvt_k<<<dim3(MODEL / 64, MODEL / 64), blk, 0, stream>>>(w_out, woT, MODEL, MODEL);
    qkv_mfma_k<<<dim3(MTOT / 128, NQKV / 128), blk, 0, stream>>>(xbf, wqT, qb, kb, vt);
    attn3_k<<<dim3(TOK / 128, NBAT * NH), blk, 0, stream>>>(qb, kb, vt, atto);
    out_mfma_k<<<dim3(MTOT / 128, MODEL / 128), blk, 0, stream>>>(atto, woT, b_out, out);
}